// Round 24
// baseline (133.083 us; speedup 1.0000x reference)
//
#include <hip/hip_runtime.h>
#include <hip/hip_bf16.h>
#include <cstdint>

typedef unsigned int u32;
typedef unsigned long long u64;
typedef __attribute__((ext_vector_type(8))) __bf16 bf16x8;
typedef __attribute__((ext_vector_type(4))) float f32x4;
typedef __attribute__((ext_vector_type(4))) _Float16 half4;
typedef __attribute__((ext_vector_type(2))) __fp16 fp16x2;

#define BT_N 256
#define F_N 256
#define C_N 256
#define H_N 4
#define D_N 64
#define TC_N 768
#define M_N (BT_N * F_N)   // 65536
#define VT_ST 268          // vt row stride (halves)
#define PL ((size_t)M_N * 128)   // qkv plane size (halves): [tn][M][128]

__device__ __forceinline__ ushort f2bf(float f) {
  u32 u = __float_as_uint(f);
  u32 r = (u + 0x7fffu + ((u >> 16) & 1u)) >> 16;
  return (ushort)r;
}

__device__ __forceinline__ u32 pkbf(float a, float b) {
  return (u32)f2bf(a) | ((u32)f2bf(b) << 16);
}

__device__ __forceinline__ void gload_lds16(const ushort* g, ushort* l) {
  __builtin_amdgcn_global_load_lds(
      (const __attribute__((address_space(1))) u32*)g,
      (__attribute__((address_space(3))) u32*)l, 16, 0, 0);
}

__device__ __forceinline__ void nt_store8(void* p, uint2 d) {
  u64 v = (u64)d.x | ((u64)d.y << 32);
  __builtin_nontemporal_store(v, (u64*)p);
}

// ---------------------------------------------------------------------------
// fp32 -> bf16 conversion: x, w_in, w_out in ONE launch (verified)
// ---------------------------------------------------------------------------
__global__ __launch_bounds__(256) void cvt3_f32_bf16_k(
    const float* __restrict__ sx, ushort* __restrict__ dx, int nx4,
    const float* __restrict__ si, ushort* __restrict__ di, int ni4,
    const float* __restrict__ so, ushort* __restrict__ dq, int no4) {
  int idx = blockIdx.x * 256 + threadIdx.x;
  int stride = gridDim.x * 256;
  int ntot = nx4 + ni4 + no4;
  for (int i = idx; i < ntot; i += stride) {
    const float4* s;
    ushort* d;
    if (i < nx4) { s = (const float4*)sx + i; d = dx + (size_t)i * 4; }
    else if (i < nx4 + ni4) { int k = i - nx4; s = (const float4*)si + k; d = di + (size_t)k * 4; }
    else { int k = i - nx4 - ni4; s = (const float4*)so + k; d = dq + (size_t)k * 4; }
    float4 v = *s;
    *(uint2*)d = make_uint2(pkbf(v.x, v.y), pkbf(v.z, v.w));
  }
}

// ---------------------------------------------------------------------------
// GEMM1 (qkv): single-buffered 32KB LDS; launch_bounds 5 waves/EU ->
// 5 blocks/CU (was 4; LDS allows 160/32=5, VGPR 64 allows 8 waves/SIMD).
// Tiled output qkv[tn][M][128].
// ---------------------------------------------------------------------------
__global__ __launch_bounds__(256, 5) void gemm_qkv_sb(
    const ushort* __restrict__ Ap, const ushort* __restrict__ Bp,
    const float* __restrict__ bias, _Float16* __restrict__ Cp,
    int NTN, int nwg8) {
  __shared__ ushort smemH[128 * 64 * 2];   // As | Bs = 32KB

  const int tid = threadIdx.x;
  const int lane = tid & 63;
  const int wid = tid >> 6;
  const int wr = wid >> 1, wc = wid & 1;
  const int l15 = lane & 15, l4 = lane >> 4;
  const int b = blockIdx.x;
  const int bid = (b & 7) * nwg8 + (b >> 3);
  const int tm = bid / NTN;
  const int tn = bid - tm * NTN;
  const int rowBase = tm * 128, colBase = tn * 128;

  f32x4 acc[4][4] = {};

  const int ar = (tid >> 3);
  const int c8 = tid & 7;
  const int akk = ((c8 ^ (ar & 7)) << 3);
  const ushort* gB = Bp + (size_t)(colBase + ar) * 256 + akk;
  const ushort* gAh = Ap + (size_t)(rowBase + ar) * 256 + akk;

#pragma unroll
  for (int t = 0; t < 4; ++t) {
    const int k0 = t * 64;
#pragma unroll
    for (int c = 0; c < 4; ++c) {
      gload_lds16(gAh + (size_t)(c * 32) * 256 + k0,
                  smemH + (size_t)(c * 256 + (wid << 6)) * 8);
      gload_lds16(gB + (size_t)(c * 32) * 256 + k0,
                  smemH + 8192 + (size_t)(c * 256 + (wid << 6)) * 8);
    }
    __syncthreads();
    const ushort* As_ = smemH;
    const ushort* Bs_ = smemH + 8192;
#pragma unroll
    for (int kk = 0; kk < 2; ++kk) {
      bf16x8 af[4];
      bf16x8 bfr[4];
#pragma unroll
      for (int i2 = 0; i2 < 4; ++i2) {
        int row = wr * 64 + i2 * 16 + l15;
        af[i2] = *(const bf16x8*)(As_ + row * 64 + (((kk * 4 + l4) ^ (l15 & 7)) * 8));
      }
#pragma unroll
      for (int j2 = 0; j2 < 4; ++j2) {
        int row = wc * 64 + j2 * 16 + l15;
        bfr[j2] = *(const bf16x8*)(Bs_ + row * 64 + (((kk * 4 + l4) ^ (l15 & 7)) * 8));
      }
#pragma unroll
      for (int i2 = 0; i2 < 4; ++i2)
#pragma unroll
        for (int j2 = 0; j2 < 4; ++j2)
          acc[i2][j2] = __builtin_amdgcn_mfma_f32_16x16x32_bf16(
              af[i2], bfr[j2], acc[i2][j2], 0, 0, 0);
    }
    __syncthreads();
  }

  // epilogue: two 64-row LDS passes (f16); contiguous tiled-plane stores
  _Float16* Ct = Cp + (size_t)tn * PL;
  ushort* eb = smemH;
#pragma unroll
  for (int pass = 0; pass < 2; ++pass) {
#pragma unroll
    for (int jh = 0; jh < 2; ++jh) {
      const int i2 = pass * 2 + jh;
#pragma unroll
      for (int j2 = 0; j2 < 4; ++j2) {
        float bv = bias[colBase + wc * 64 + j2 * 16 + l15];
#pragma unroll
        for (int r = 0; r < 4; ++r) {
          _Float16 h = (_Float16)(acc[i2][j2][r] + bv);
          eb[(wr * 32 + jh * 16 + l4 * 4 + r) * 136 + wc * 64 + j2 * 16 + l15] =
              __builtin_bit_cast(ushort, h);
        }
      }
    }
    __syncthreads();
#pragma unroll
    for (int i = 0; i < 8; ++i) {
      int br = wid * 16 + 2 * i + (lane >> 5);
      int hl = lane & 31;
      uint2 d = *(const uint2*)(eb + br * 136 + hl * 4);
      int grow = rowBase + (br >> 5) * 64 + pass * 32 + (br & 31);
      *(uint2*)(Ct + (size_t)grow * 128 + hl * 4) = d;
    }
    __syncthreads();
  }
}

// ---------------------------------------------------------------------------
// GEMM2 (y = attn @ w_out^T + b_out): single-buffered, f32 out, NT stores.
// ---------------------------------------------------------------------------
__global__ __launch_bounds__(256, 4) void gemm_out_sb(
    const ushort* __restrict__ Ap, const ushort* __restrict__ Bp,
    const float* __restrict__ bias, float* __restrict__ Cp,
    int NTN, int nwg8) {
  __shared__ char smem[64 * 132 * 4];
  ushort* smemH = (ushort*)smem;

  const int tid = threadIdx.x;
  const int lane = tid & 63;
  const int wid = tid >> 6;
  const int wr = wid >> 1, wc = wid & 1;
  const int l15 = lane & 15, l4 = lane >> 4;
  const int b = blockIdx.x;
  const int bid = (b & 7) * nwg8 + (b >> 3);
  const int tm = bid / NTN;
  const int tn = bid - tm * NTN;
  const int rowBase = tm * 128, colBase = tn * 128;

  f32x4 acc[4][4] = {};

  const int ar = (tid >> 3);
  const int c8 = tid & 7;
  const int akk = ((c8 ^ (ar & 7)) << 3);
  const ushort* gB = Bp + (size_t)(colBase + ar) * 256 + akk;
  const ushort* gAh = Ap + (size_t)(rowBase + ar) * 256 + akk;

#pragma unroll
  for (int t = 0; t < 4; ++t) {
    const int k0 = t * 64;
#pragma unroll
    for (int c = 0; c < 4; ++c) {
      gload_lds16(gAh + (size_t)(c * 32) * 256 + k0,
                  smemH + (size_t)(c * 256 + (wid << 6)) * 8);
      gload_lds16(gB + (size_t)(c * 32) * 256 + k0,
                  smemH + 8192 + (size_t)(c * 256 + (wid << 6)) * 8);
    }
    __syncthreads();
    const ushort* As_ = smemH;
    const ushort* Bs_ = smemH + 8192;
#pragma unroll
    for (int kk = 0; kk < 2; ++kk) {
      bf16x8 af[4];
      bf16x8 bfr[4];
#pragma unroll
      for (int i2 = 0; i2 < 4; ++i2) {
        int row = wr * 64 + i2 * 16 + l15;
        af[i2] = *(const bf16x8*)(As_ + row * 64 + (((kk * 4 + l4) ^ (l15 & 7)) * 8));
      }
#pragma unroll
      for (int j2 = 0; j2 < 4; ++j2) {
        int row = wc * 64 + j2 * 16 + l15;
        bfr[j2] = *(const bf16x8*)(Bs_ + row * 64 + (((kk * 4 + l4) ^ (l15 & 7)) * 8));
      }
#pragma unroll
      for (int i2 = 0; i2 < 4; ++i2)
#pragma unroll
        for (int j2 = 0; j2 < 4; ++j2)
          acc[i2][j2] = __builtin_amdgcn_mfma_f32_16x16x32_bf16(
              af[i2], bfr[j2], acc[i2][j2], 0, 0, 0);
    }
    __syncthreads();
  }

  float* eb = (float*)smem;
#pragma unroll
  for (int pass = 0; pass < 2; ++pass) {
#pragma unroll
    for (int jh = 0; jh < 2; ++jh) {
      const int i2 = pass * 2 + jh;
#pragma unroll
      for (int j2 = 0; j2 < 4; ++j2) {
        float bv = bias[colBase + wc * 64 + j2 * 16 + l15];
#pragma unroll
        for (int r = 0; r < 4; ++r)
          eb[(wr * 32 + jh * 16 + l4 * 4 + r) * 132 + wc * 64 + j2 * 16 + l15] =
              acc[i2][j2][r] + bv;
      }
    }
    __syncthreads();
#pragma unroll
    for (int i = 0; i < 16; ++i) {
      int br = wid * 16 + i;
      uint2 d = *(const uint2*)((const u32*)eb + br * 132 + lane * 2);
      int grow = rowBase + (br >> 5) * 64 + pass * 32 + (br & 31);
      nt_store8(Cp + (size_t)grow * C_N + colBase + lane * 2, d);
    }
    __syncthreads();
  }
}

// ---------------------------------------------------------------------------
// Banded attention via MFMA (r23-verified, tiled qkv planes).
// ---------------------------------------------------------------------------
__global__ __launch_bounds__(256) void attn_mfma(
    const _Float16* __restrict__ qkv, ushort* __restrict__ aout) {
  __shared__ ushort smem[18432 + 64 * VT_ST];
  const int tid = threadIdx.x;
  const int bt = blockIdx.x >> 2;
  const int h = blockIdx.x & 3;
  const size_t rb = (size_t)(bt * 256) * 128;
  const int co = (h & 1) * 64;
  const _Float16* qb = qkv + (size_t)(h >> 1) * PL + rb + co;
  const _Float16* kb = qkv + (size_t)(2 + (h >> 1)) * PL + rb + co;
  const _Float16* vb = qkv + (size_t)(4 + (h >> 1)) * PL + rb + co;
  ushort* klds = smem;
  ushort* vlds = smem + 18432;

  {
    const int r0 = tid >> 3, c8 = tid & 7;
    const int pr2 = tid >> 4, dq = tid & 15;
#pragma unroll
    for (int p = 0; p < 8; ++p) {
      int j = p * 32 + r0;
      const uint4 k4 = *(const uint4*)(kb + (size_t)j * 128 + c8 * 8);
      *(uint4*)(klds + j * 72 + c8 * 8) = k4;
      int j0 = p * 32 + pr2 * 2;
      uint2 va = *(const uint2*)(vb + (size_t)j0 * 128 + dq * 4);
      uint2 vbv = *(const uint2*)(vb + (size_t)(j0 + 1) * 128 + dq * 4);
      u32 w0 = (va.x & 0xffffu) | (vbv.x << 16);
      u32 w1 = (va.x >> 16) | (vbv.x & 0xffff0000u);
      u32 w2 = (va.y & 0xffffu) | (vbv.y << 16);
      u32 w3 = (va.y >> 16) | (vbv.y & 0xffff0000u);
      int d0 = dq * 4;
      *(u32*)(vlds + (d0 + 0) * VT_ST + j0) = w0;
      *(u32*)(vlds + (d0 + 1) * VT_ST + j0) = w1;
      *(u32*)(vlds + (d0 + 2) * VT_ST + j0) = w2;
      *(u32*)(vlds + (d0 + 3) * VT_ST + j0) = w3;
    }
  }

  const int w = tid >> 6, lane = tid & 63;
  const int l15 = lane & 15, g = lane >> 4, g4 = g * 4;

  uint2 qf0[4], qf1[4], qf2[4], qf3[4];
  {
    const uint2* q0 = (const uint2*)(qb + (size_t)(w * 64 + 0 * 16 + l15) * 128 + g4);
    const uint2* q1 = (const uint2*)(qb + (size_t)(w * 64 + 1 * 16 + l15) * 128 + g4);
    const uint2* q2 = (const uint2*)(qb + (size_t)(w * 64 + 2 * 16 + l15) * 128 + g4);
    const uint2* q3 = (const uint2*)(qb + (size_t)(w * 64 + 3 * 16 + l15) * 128 + g4);
#pragma unroll
    for (int ks = 0; ks < 4; ++ks) {
      qf0[ks] = q0[ks * 4]; qf1[ks] = q1[ks * 4];
      qf2[ks] = q2[ks * 4]; qf3[ks] = q3[ks * 4];
    }
  }

  u32 bb = 0;
#pragma unroll
  for (int jt = 0; jt < 3; ++jt)
#pragma unroll
    for (int r = 0; r < 4; ++r) {
      int d = 16 * jt + g4 + r - 16 - l15;
      if (d >= -16 && d <= 16) bb |= 1u << (jt * 4 + r);
    }

  __syncthreads();

  const float SC = 0.18033688f;  // 0.125 * log2(e)

#pragma unroll
  for (int rt = 0; rt < 4; ++rt) {
    const int R0 = w * 64 + rt * 16;
    const int Jc = R0 - 16;
    const uint2* qf = (rt == 0) ? qf0 : (rt == 1) ? qf1 : (rt == 2) ? qf2 : qf3;

    f32x4 st[3] = {};
#pragma unroll
    for (int jt = 0; jt < 3; ++jt) {
      int krow = Jc + 16 * jt + l15;
      krow = krow < 0 ? 0 : (krow > 255 ? 255 : krow);
      const ushort* kp = klds + krow * 72 + g4;
#pragma unroll
      for (int ks = 0; ks < 4; ++ks) {
        uint2 kf = *(const uint2*)(kp + ks * 16);
        st[jt] = __builtin_amdgcn_mfma_f32_16x16x16f16(
            __builtin_bit_cast(half4, kf), __builtin_bit_cast(half4, qf[ks]),
            st[jt], 0, 0, 0);
      }
    }

    float l_acc = 0.f;
    float pp[3][4];
#pragma unroll
    for (int jt = 0; jt < 3; ++jt)
#pragma unroll
      for (int r = 0; r < 4; ++r) {
        int jg = Jc + 16 * jt + g4 + r;
        bool keep = (((bb >> (jt * 4 + r)) & 1u) != 0) && (jg >= 0) && (jg < 256);
        float pv = keep ? __builtin_amdgcn_exp2f(st[jt][r] * SC) : 0.f;
        pp[jt][r] = pv;
        l_acc += pv;
      }
    l_acc += __shfl_xor(l_acc, 16, 64);
    l_acc += __shfl_xor(l_acc, 32, 64);
    const float inv = 1.f / l_acc;

    uint2 pf[3];
#pragma unroll
    for (int jt = 0; jt < 3; ++jt) {
      fp16x2 a = __builtin_amdgcn_cvt_pkrtz(pp[jt][0] * inv, pp[jt][1] * inv);
      fp16x2 c = __builtin_amdgcn_cvt_pkrtz(pp[jt][2] * inv, pp[jt][3] * inv);
      pf[jt].x = __builtin_bit_cast(u32, a);
      pf[jt].y = __builtin_bit_cast(u32, c);
    }

    f32x4 ot[4] = {};
#pragma unroll
    for (int kt = 0; kt < 3; ++kt) {
      int jb = Jc + 16 * kt + g4;
      jb = jb < 0 ? 0 : (jb > 252 ? 252 : jb);
#pragma unroll
      for (int mt = 0; mt < 4; ++mt) {
        uint2 vfr = *(const uint2*)(vlds + (16 * mt + l15) * VT_ST + jb);
        ot[mt] = __builtin_amdgcn_mfma_f32_16x16x16f16(
            __builtin_bit_cast(half4, vfr), __builtin_bit_cast(half4, pf[kt]),
            ot[mt], 0, 0, 0);
      }
    }

    ushort* orow = aout + (size_t)(bt * 256 + R0 + l15) * 256 + h * 64 + g4;
#pragma unroll
    for (int mt = 0; mt < 4; ++mt) {
      u32 lo = (u32)f2bf(ot[mt][0]) | ((u32)f2bf(ot[mt][1]) << 16);
      u32 hi = (u32)f2bf(ot[mt][2]) | ((u32)f2bf(ot[mt][3]) << 16);
      *(uint2*)(orow + mt * 16) = make_uint2(lo, hi);
    }
  }
}

// ---------------------------------------------------------------------------
extern "C" void kernel_launch(void* const* d_in, const int* in_sizes, int n_in,
                              void* d_out, int out_size, void* d_ws, size_t ws_size,
                              hipStream_t stream) {
  const float* x = (const float*)d_in[0];
  const float* w_in = (const float*)d_in[1];
  const float* b_in = (const float*)d_in[2];
  const float* w_out = (const float*)d_in[3];
  const float* b_out = (const float*)d_in[4];
  float* y = (float*)d_out;

  char* ws = (char*)d_ws;
  const size_t qkv_bytes = (size_t)M_N * TC_N * 2;
  const size_t xb_bytes = (size_t)M_N * C_N * 2;
  _Float16* qkv = (_Float16*)ws;   // tiled: [tn 0..5][M][128]
  ushort* xb = (ushort*)(ws + qkv_bytes);
  ushort* attn = xb;  // aliased: xb dead after gemm1
  ushort* winb = (ushort*)(ws + qkv_bytes + xb_bytes);
  ushort* woutb = winb + TC_N * C_N;

  // x + weights fp32 -> bf16 (single launch)
  cvt3_f32_bf16_k<<<2048, 256, 0, stream>>>(x, xb, M_N * C_N / 4,
                                            w_in, winb, TC_N * C_N / 4,
                                            w_out, woutb, C_N * C_N / 4);

  // qkv = x @ w_in^T + b_in  (f16 out, tiled planes; cached stores)
  gemm_qkv_sb<<<(M_N / 128) * (TC_N / 128), 256, 0, stream>>>(
      xb, winb, b_in, qkv, TC_N / 128, (M_N / 128) * (TC_N / 128) / 8);

  // banded attention (bf16 out)
  attn_mfma<<<BT_N * H_N, 256, 0, stream>>>(qkv, attn);

  // y = attn @ w_out^T + b_out  (fp32 out; NT — y never re-read)
  gemm_out_sb<<<(M_N / 128) * (C_N / 128), 256, 0, stream>>>(
      attn, woutb, b_out, y, C_N / 128, (M_N / 128) * (C_N / 128) / 8);
}

// Round 25
// 98.248 us; speedup vs baseline: 1.3546x; 1.3546x over previous
//
#include <hip/hip_runtime.h>
#include <hip/hip_bf16.h>
#include <cstdint>

typedef unsigned int u32;
typedef unsigned long long u64;
typedef __attribute__((ext_vector_type(8))) __bf16 bf16x8;
typedef __attribute__((ext_vector_type(4))) float f32x4;
typedef __attribute__((ext_vector_type(4))) _Float16 half4;
typedef __attribute__((ext_vector_type(2))) __fp16 fp16x2;

#define BT_N 256
#define F_N 256
#define C_N 256
#define H_N 4
#define D_N 64
#define TC_N 768
#define M_N (BT_N * F_N)   // 65536
#define VT_ST 268          // vt row stride (halves)
#define PL ((size_t)M_N * 128)   // qkv plane size (halves): [tn][M][128]

__device__ __forceinline__ ushort f2bf(float f) {
  u32 u = __float_as_uint(f);
  u32 r = (u + 0x7fffu + ((u >> 16) & 1u)) >> 16;
  return (ushort)r;
}

__device__ __forceinline__ u32 pkbf(float a, float b) {
  return (u32)f2bf(a) | ((u32)f2bf(b) << 16);
}

__device__ __forceinline__ void gload_lds16(const ushort* g, ushort* l) {
  __builtin_amdgcn_global_load_lds(
      (const __attribute__((address_space(1))) u32*)g,
      (__attribute__((address_space(3))) u32*)l, 16, 0, 0);
}

__device__ __forceinline__ void nt_store8(void* p, uint2 d) {
  u64 v = (u64)d.x | ((u64)d.y << 32);
  __builtin_nontemporal_store(v, (u64*)p);
}

// ---------------------------------------------------------------------------
// fp32 -> bf16 conversion: x, w_in, w_out in ONE launch (verified)
// ---------------------------------------------------------------------------
__global__ __launch_bounds__(256) void cvt3_f32_bf16_k(
    const float* __restrict__ sx, ushort* __restrict__ dx, int nx4,
    const float* __restrict__ si, ushort* __restrict__ di, int ni4,
    const float* __restrict__ so, ushort* __restrict__ dq, int no4) {
  int idx = blockIdx.x * 256 + threadIdx.x;
  int stride = gridDim.x * 256;
  int ntot = nx4 + ni4 + no4;
  for (int i = idx; i < ntot; i += stride) {
    const float4* s;
    ushort* d;
    if (i < nx4) { s = (const float4*)sx + i; d = dx + (size_t)i * 4; }
    else if (i < nx4 + ni4) { int k = i - nx4; s = (const float4*)si + k; d = di + (size_t)k * 4; }
    else { int k = i - nx4 - ni4; s = (const float4*)so + k; d = dq + (size_t)k * 4; }
    float4 v = *s;
    *(uint2*)d = make_uint2(pkbf(v.x, v.y), pkbf(v.z, v.w));
  }
}

// ---------------------------------------------------------------------------
// GEMM1 (qkv): single-buffered 32KB LDS, 4 blocks/CU (r17/r18/r22-verified;
// (256,5) spills VGPR->scratch, r24).  Tiled output qkv[tn][M][128].
// ---------------------------------------------------------------------------
__global__ __launch_bounds__(256, 4) void gemm_qkv_sb(
    const ushort* __restrict__ Ap, const ushort* __restrict__ Bp,
    const float* __restrict__ bias, _Float16* __restrict__ Cp,
    int NTN, int nwg8) {
  __shared__ ushort smemH[128 * 64 * 2];   // As | Bs = 32KB

  const int tid = threadIdx.x;
  const int lane = tid & 63;
  const int wid = tid >> 6;
  const int wr = wid >> 1, wc = wid & 1;
  const int l15 = lane & 15, l4 = lane >> 4;
  const int b = blockIdx.x;
  const int bid = (b & 7) * nwg8 + (b >> 3);
  const int tm = bid / NTN;
  const int tn = bid - tm * NTN;
  const int rowBase = tm * 128, colBase = tn * 128;

  f32x4 acc[4][4] = {};

  const int ar = (tid >> 3);
  const int c8 = tid & 7;
  const int akk = ((c8 ^ (ar & 7)) << 3);
  const ushort* gB = Bp + (size_t)(colBase + ar) * 256 + akk;
  const ushort* gAh = Ap + (size_t)(rowBase + ar) * 256 + akk;

#pragma unroll
  for (int t = 0; t < 4; ++t) {
    const int k0 = t * 64;
#pragma unroll
    for (int c = 0; c < 4; ++c) {
      gload_lds16(gAh + (size_t)(c * 32) * 256 + k0,
                  smemH + (size_t)(c * 256 + (wid << 6)) * 8);
      gload_lds16(gB + (size_t)(c * 32) * 256 + k0,
                  smemH + 8192 + (size_t)(c * 256 + (wid << 6)) * 8);
    }
    __syncthreads();
    const ushort* As_ = smemH;
    const ushort* Bs_ = smemH + 8192;
#pragma unroll
    for (int kk = 0; kk < 2; ++kk) {
      bf16x8 af[4];
      bf16x8 bfr[4];
#pragma unroll
      for (int i2 = 0; i2 < 4; ++i2) {
        int row = wr * 64 + i2 * 16 + l15;
        af[i2] = *(const bf16x8*)(As_ + row * 64 + (((kk * 4 + l4) ^ (l15 & 7)) * 8));
      }
#pragma unroll
      for (int j2 = 0; j2 < 4; ++j2) {
        int row = wc * 64 + j2 * 16 + l15;
        bfr[j2] = *(const bf16x8*)(Bs_ + row * 64 + (((kk * 4 + l4) ^ (l15 & 7)) * 8));
      }
#pragma unroll
      for (int i2 = 0; i2 < 4; ++i2)
#pragma unroll
        for (int j2 = 0; j2 < 4; ++j2)
          acc[i2][j2] = __builtin_amdgcn_mfma_f32_16x16x32_bf16(
              af[i2], bfr[j2], acc[i2][j2], 0, 0, 0);
    }
    __syncthreads();
  }

  // epilogue: two 64-row LDS passes (f16); contiguous tiled-plane stores
  _Float16* Ct = Cp + (size_t)tn * PL;
  ushort* eb = smemH;
#pragma unroll
  for (int pass = 0; pass < 2; ++pass) {
#pragma unroll
    for (int jh = 0; jh < 2; ++jh) {
      const int i2 = pass * 2 + jh;
#pragma unroll
      for (int j2 = 0; j2 < 4; ++j2) {
        float bv = bias[colBase + wc * 64 + j2 * 16 + l15];
#pragma unroll
        for (int r = 0; r < 4; ++r) {
          _Float16 h = (_Float16)(acc[i2][j2][r] + bv);
          eb[(wr * 32 + jh * 16 + l4 * 4 + r) * 136 + wc * 64 + j2 * 16 + l15] =
              __builtin_bit_cast(ushort, h);
        }
      }
    }
    __syncthreads();
#pragma unroll
    for (int i = 0; i < 8; ++i) {
      int br = wid * 16 + 2 * i + (lane >> 5);
      int hl = lane & 31;
      uint2 d = *(const uint2*)(eb + br * 136 + hl * 4);
      int grow = rowBase + (br >> 5) * 64 + pass * 32 + (br & 31);
      *(uint2*)(Ct + (size_t)grow * 128 + hl * 4) = d;
    }
    __syncthreads();
  }
}

// ---------------------------------------------------------------------------
// GEMM2 (y = attn @ w_out^T + b_out): single-buffered, f32 out, NT stores.
// ---------------------------------------------------------------------------
__global__ __launch_bounds__(256, 4) void gemm_out_sb(
    const ushort* __restrict__ Ap, const ushort* __restrict__ Bp,
    const float* __restrict__ bias, float* __restrict__ Cp,
    int NTN, int nwg8) {
  __shared__ char smem[64 * 132 * 4];
  ushort* smemH = (ushort*)smem;

  const int tid = threadIdx.x;
  const int lane = tid & 63;
  const int wid = tid >> 6;
  const int wr = wid >> 1, wc = wid & 1;
  const int l15 = lane & 15, l4 = lane >> 4;
  const int b = blockIdx.x;
  const int bid = (b & 7) * nwg8 + (b >> 3);
  const int tm = bid / NTN;
  const int tn = bid - tm * NTN;
  const int rowBase = tm * 128, colBase = tn * 128;

  f32x4 acc[4][4] = {};

  const int ar = (tid >> 3);
  const int c8 = tid & 7;
  const int akk = ((c8 ^ (ar & 7)) << 3);
  const ushort* gB = Bp + (size_t)(colBase + ar) * 256 + akk;
  const ushort* gAh = Ap + (size_t)(rowBase + ar) * 256 + akk;

#pragma unroll
  for (int t = 0; t < 4; ++t) {
    const int k0 = t * 64;
#pragma unroll
    for (int c = 0; c < 4; ++c) {
      gload_lds16(gAh + (size_t)(c * 32) * 256 + k0,
                  smemH + (size_t)(c * 256 + (wid << 6)) * 8);
      gload_lds16(gB + (size_t)(c * 32) * 256 + k0,
                  smemH + 8192 + (size_t)(c * 256 + (wid << 6)) * 8);
    }
    __syncthreads();
    const ushort* As_ = smemH;
    const ushort* Bs_ = smemH + 8192;
#pragma unroll
    for (int kk = 0; kk < 2; ++kk) {
      bf16x8 af[4];
      bf16x8 bfr[4];
#pragma unroll
      for (int i2 = 0; i2 < 4; ++i2) {
        int row = wr * 64 + i2 * 16 + l15;
        af[i2] = *(const bf16x8*)(As_ + row * 64 + (((kk * 4 + l4) ^ (l15 & 7)) * 8));
      }
#pragma unroll
      for (int j2 = 0; j2 < 4; ++j2) {
        int row = wc * 64 + j2 * 16 + l15;
        bfr[j2] = *(const bf16x8*)(Bs_ + row * 64 + (((kk * 4 + l4) ^ (l15 & 7)) * 8));
      }
#pragma unroll
      for (int i2 = 0; i2 < 4; ++i2)
#pragma unroll
        for (int j2 = 0; j2 < 4; ++j2)
          acc[i2][j2] = __builtin_amdgcn_mfma_f32_16x16x32_bf16(
              af[i2], bfr[j2], acc[i2][j2], 0, 0, 0);
    }
    __syncthreads();
  }

  float* eb = (float*)smem;
#pragma unroll
  for (int pass = 0; pass < 2; ++pass) {
#pragma unroll
    for (int jh = 0; jh < 2; ++jh) {
      const int i2 = pass * 2 + jh;
#pragma unroll
      for (int j2 = 0; j2 < 4; ++j2) {
        float bv = bias[colBase + wc * 64 + j2 * 16 + l15];
#pragma unroll
        for (int r = 0; r < 4; ++r)
          eb[(wr * 32 + jh * 16 + l4 * 4 + r) * 132 + wc * 64 + j2 * 16 + l15] =
              acc[i2][j2][r] + bv;
      }
    }
    __syncthreads();
#pragma unroll
    for (int i = 0; i < 16; ++i) {
      int br = wid * 16 + i;
      uint2 d = *(const uint2*)((const u32*)eb + br * 132 + lane * 2);
      int grow = rowBase + (br >> 5) * 64 + pass * 32 + (br & 31);
      nt_store8(Cp + (size_t)grow * C_N + colBase + lane * 2, d);
    }
    __syncthreads();
  }
}

// ---------------------------------------------------------------------------
// Banded attention via MFMA (r23-verified, tiled qkv planes).
// ---------------------------------------------------------------------------
__global__ __launch_bounds__(256) void attn_mfma(
    const _Float16* __restrict__ qkv, ushort* __restrict__ aout) {
  __shared__ ushort smem[18432 + 64 * VT_ST];
  const int tid = threadIdx.x;
  const int bt = blockIdx.x >> 2;
  const int h = blockIdx.x & 3;
  const size_t rb = (size_t)(bt * 256) * 128;
  const int co = (h & 1) * 64;
  const _Float16* qb = qkv + (size_t)(h >> 1) * PL + rb + co;
  const _Float16* kb = qkv + (size_t)(2 + (h >> 1)) * PL + rb + co;
  const _Float16* vb = qkv + (size_t)(4 + (h >> 1)) * PL + rb + co;
  ushort* klds = smem;
  ushort* vlds = smem + 18432;

  {
    const int r0 = tid >> 3, c8 = tid & 7;
    const int pr2 = tid >> 4, dq = tid & 15;
#pragma unroll
    for (int p = 0; p < 8; ++p) {
      int j = p * 32 + r0;
      const uint4 k4 = *(const uint4*)(kb + (size_t)j * 128 + c8 * 8);
      *(uint4*)(klds + j * 72 + c8 * 8) = k4;
      int j0 = p * 32 + pr2 * 2;
      uint2 va = *(const uint2*)(vb + (size_t)j0 * 128 + dq * 4);
      uint2 vbv = *(const uint2*)(vb + (size_t)(j0 + 1) * 128 + dq * 4);
      u32 w0 = (va.x & 0xffffu) | (vbv.x << 16);
      u32 w1 = (va.x >> 16) | (vbv.x & 0xffff0000u);
      u32 w2 = (va.y & 0xffffu) | (vbv.y << 16);
      u32 w3 = (va.y >> 16) | (vbv.y & 0xffff0000u);
      int d0 = dq * 4;
      *(u32*)(vlds + (d0 + 0) * VT_ST + j0) = w0;
      *(u32*)(vlds + (d0 + 1) * VT_ST + j0) = w1;
      *(u32*)(vlds + (d0 + 2) * VT_ST + j0) = w2;
      *(u32*)(vlds + (d0 + 3) * VT_ST + j0) = w3;
    }
  }

  const int w = tid >> 6, lane = tid & 63;
  const int l15 = lane & 15, g = lane >> 4, g4 = g * 4;

  uint2 qf0[4], qf1[4], qf2[4], qf3[4];
  {
    const uint2* q0 = (const uint2*)(qb + (size_t)(w * 64 + 0 * 16 + l15) * 128 + g4);
    const uint2* q1 = (const uint2*)(qb + (size_t)(w * 64 + 1 * 16 + l15) * 128 + g4);
    const uint2* q2 = (const uint2*)(qb + (size_t)(w * 64 + 2 * 16 + l15) * 128 + g4);
    const uint2* q3 = (const uint2*)(qb + (size_t)(w * 64 + 3 * 16 + l15) * 128 + g4);
#pragma unroll
    for (int ks = 0; ks < 4; ++ks) {
      qf0[ks] = q0[ks * 4]; qf1[ks] = q1[ks * 4];
      qf2[ks] = q2[ks * 4]; qf3[ks] = q3[ks * 4];
    }
  }

  u32 bb = 0;
#pragma unroll
  for (int jt = 0; jt < 3; ++jt)
#pragma unroll
    for (int r = 0; r < 4; ++r) {
      int d = 16 * jt + g4 + r - 16 - l15;
      if (d >= -16 && d <= 16) bb |= 1u << (jt * 4 + r);
    }

  __syncthreads();

  const float SC = 0.18033688f;  // 0.125 * log2(e)

#pragma unroll
  for (int rt = 0; rt < 4; ++rt) {
    const int R0 = w * 64 + rt * 16;
    const int Jc = R0 - 16;
    const uint2* qf = (rt == 0) ? qf0 : (rt == 1) ? qf1 : (rt == 2) ? qf2 : qf3;

    f32x4 st[3] = {};
#pragma unroll
    for (int jt = 0; jt < 3; ++jt) {
      int krow = Jc + 16 * jt + l15;
      krow = krow < 0 ? 0 : (krow > 255 ? 255 : krow);
      const ushort* kp = klds + krow * 72 + g4;
#pragma unroll
      for (int ks = 0; ks < 4; ++ks) {
        uint2 kf = *(const uint2*)(kp + ks * 16);
        st[jt] = __builtin_amdgcn_mfma_f32_16x16x16f16(
            __builtin_bit_cast(half4, kf), __builtin_bit_cast(half4, qf[ks]),
            st[jt], 0, 0, 0);
      }
    }

    float l_acc = 0.f;
    float pp[3][4];
#pragma unroll
    for (int jt = 0; jt < 3; ++jt)
#pragma unroll
      for (int r = 0; r < 4; ++r) {
        int jg = Jc + 16 * jt + g4 + r;
        bool keep = (((bb >> (jt * 4 + r)) & 1u) != 0) && (jg >= 0) && (jg < 256);
        float pv = keep ? __builtin_amdgcn_exp2f(st[jt][r] * SC) : 0.f;
        pp[jt][r] = pv;
        l_acc += pv;
      }
    l_acc += __shfl_xor(l_acc, 16, 64);
    l_acc += __shfl_xor(l_acc, 32, 64);
    const float inv = 1.f / l_acc;

    uint2 pf[3];
#pragma unroll
    for (int jt = 0; jt < 3; ++jt) {
      fp16x2 a = __builtin_amdgcn_cvt_pkrtz(pp[jt][0] * inv, pp[jt][1] * inv);
      fp16x2 c = __builtin_amdgcn_cvt_pkrtz(pp[jt][2] * inv, pp[jt][3] * inv);
      pf[jt].x = __builtin_bit_cast(u32, a);
      pf[jt].y = __builtin_bit_cast(u32, c);
    }

    f32x4 ot[4] = {};
#pragma unroll
    for (int kt = 0; kt < 3; ++kt) {
      int jb = Jc + 16 * kt + g4;
      jb = jb < 0 ? 0 : (jb > 252 ? 252 : jb);
#pragma unroll
      for (int mt = 0; mt < 4; ++mt) {
        uint2 vfr = *(const uint2*)(vlds + (16 * mt + l15) * VT_ST + jb);
        ot[mt] = __builtin_amdgcn_mfma_f32_16x16x16f16(
            __builtin_bit_cast(half4, vfr), __builtin_bit_cast(half4, pf[kt]),
            ot[mt], 0, 0, 0);
      }
    }

    ushort* orow = aout + (size_t)(bt * 256 + R0 + l15) * 256 + h * 64 + g4;
#pragma unroll
    for (int mt = 0; mt < 4; ++mt) {
      u32 lo = (u32)f2bf(ot[mt][0]) | ((u32)f2bf(ot[mt][1]) << 16);
      u32 hi = (u32)f2bf(ot[mt][2]) | ((u32)f2bf(ot[mt][3]) << 16);
      *(uint2*)(orow + mt * 16) = make_uint2(lo, hi);
    }
  }
}

// ---------------------------------------------------------------------------
extern "C" void kernel_launch(void* const* d_in, const int* in_sizes, int n_in,
                              void* d_out, int out_size, void* d_ws, size_t ws_size,
                              hipStream_t stream) {
  const float* x = (const float*)d_in[0];
  const float* w_in = (const float*)d_in[1];
  const float* b_in = (const float*)d_in[2];
  const float* w_out = (const float*)d_in[3];
  const float* b_out = (const float*)d_in[4];
  float* y = (float*)d_out;

  char* ws = (char*)d_ws;
  const size_t qkv_bytes = (size_t)M_N * TC_N * 2;
  const size_t xb_bytes = (size_t)M_N * C_N * 2;
  _Float16* qkv = (_Float16*)ws;   // tiled: [tn 0..5][M][128]
  ushort* xb = (ushort*)(ws + qkv_bytes);
  ushort* attn = xb;  // aliased: xb dead after gemm1
  ushort* winb = (ushort*)(ws + qkv_bytes + xb_bytes);
  ushort* woutb = winb + TC_N * C_N;

  // x + weights fp32 -> bf16 (single launch)
  cvt3_f32_bf16_k<<<2048, 256, 0, stream>>>(x, xb, M_N * C_N / 4,
                                            w_in, winb, TC_N * C_N / 4,
                                            w_out, woutb, C_N * C_N / 4);

  // qkv = x @ w_in^T + b_in  (f16 out, tiled planes; cached stores)
  gemm_qkv_sb<<<(M_N / 128) * (TC_N / 128), 256, 0, stream>>>(
      xb, winb, b_in, qkv, TC_N / 128, (M_N / 128) * (TC_N / 128) / 8);

  // banded attention (bf16 out)
  attn_mfma<<<BT_N * H_N, 256, 0, stream>>>(qkv, attn);

  // y = attn @ w_out^T + b_out  (fp32 out; NT — y never re-read)
  gemm_out_sb<<<(M_N / 128) * (C_N / 128), 256, 0, stream>>>(
      attn, woutb, b_out, y, C_N / 128, (M_N / 128) * (C_N / 128) / 8);
}